// Round 8
// baseline (560.405 us; speedup 1.0000x reference)
//
#include <hip/hip_runtime.h>
#include <math.h>

#define N_NODES 8192
#define NFEAT 256
#define NHID 64
#define NHEADS 4
#define NCLASS 121
#define NCPAD 128
#define CAP 256
#define LRALPHA 0.2f

typedef float f32x4 __attribute__((ext_vector_type(4)));
typedef _Float16 f16;
typedef _Float16 f16x4 __attribute__((ext_vector_type(4)));

__device__ __forceinline__ float lrelu(float x) { return x > 0.f ? x : LRALPHA * x; }
__device__ __forceinline__ f32x4 splat4(float v) { f32x4 r = {v, v, v, v}; return r; }

// ---------------------------------------------------------------------------
// Kernel A: gemm1 (64-row tile, blocks 0..511) with fused coef1 epilogue,
// then build_csr (8 rows/block, all 1024 blocks), then param padding.
// csr blocks (>=512) start streaming adj immediately, overlapping with gemm.
// ---------------------------------------------------------------------------
__global__ __launch_bounds__(256) void phaseA(
    const float* __restrict__ x, const float* __restrict__ adj,
    const float* __restrict__ Ws, const float* __restrict__ a_heads,
    const float* __restrict__ Wout, const float* __restrict__ aout,
    int* __restrict__ nbr, int* __restrict__ deg,
    f16* __restrict__ Wh1h, float* __restrict__ fs1t, float* __restrict__ fd1t,
    float* __restrict__ Wpad, float* __restrict__ apad)
{
    __shared__ union { float xs[64][260]; int cnt; } sm;
    const int tid = threadIdx.x;

    // ---- A1: gemm1 + coef1 epilogue (512 tasks: 128 r0-tiles x 4 heads) ----
    if (blockIdx.x < 512) {
        int h = blockIdx.x & 3;
        int r0 = (blockIdx.x >> 2) * 64;
        for (int t = tid; t < 64 * 64; t += 256) {
            int r = t >> 6, c4 = t & 63;
            *(float4*)&sm.xs[r][c4 * 4] = *(const float4*)(x + (size_t)(r0 + r) * NFEAT + c4 * 4);
        }
        __syncthreads();
        int d = tid & 63;
        int rb = (tid >> 6) * 16;
        const float* W = Ws + (size_t)h * NFEAT * NHID + d;  // W[k][d]
        float acc[16] = {};
        for (int k4 = 0; k4 < NFEAT; k4 += 4) {
            float b0 = W[(k4 + 0) * NHID];
            float b1 = W[(k4 + 1) * NHID];
            float b2 = W[(k4 + 2) * NHID];
            float b3 = W[(k4 + 3) * NHID];
#pragma unroll
            for (int r = 0; r < 16; r++) {
                float4 a = *(const float4*)&sm.xs[rb + r][k4];
                acc[r] += a.x * b0 + a.y * b1 + a.z * b2 + a.w * b3;
            }
        }
        float ah_s = a_heads[h * 2 * NHID + d];
        float ah_d = a_heads[h * 2 * NHID + NHID + d];
#pragma unroll
        for (int r = 0; r < 16; r++) {
            int row = r0 + rb + r;
            Wh1h[(size_t)row * (NHEADS * NHID) + h * NHID + d] = (f16)acc[r];
            float s = acc[r] * ah_s;
            float dd = acc[r] * ah_d;
#pragma unroll
            for (int o = 32; o > 0; o >>= 1) { s += __shfl_xor(s, o); dd += __shfl_xor(dd, o); }
            if (d == 0) { fs1t[(size_t)row * 4 + h] = s; fd1t[(size_t)row * 4 + h] = dd; }
        }
        __syncthreads();   // xs reads done before union reuse as cnt
    }

    // ---- A2: build_csr, 8 rows per block ----
    for (int row = blockIdx.x; row < N_NODES; row += gridDim.x) {
        if (tid == 0) sm.cnt = 0;
        __syncthreads();
        const f32x4* arow = (const f32x4*)(adj + (size_t)row * N_NODES);
        for (int j4 = tid; j4 < N_NODES / 4; j4 += 256) {
            f32x4 v = __builtin_nontemporal_load(&arow[j4]);
            if (v.x > 0.f) { int s = atomicAdd(&sm.cnt, 1); if (s < CAP) nbr[row * CAP + s] = j4 * 4 + 0; }
            if (v.y > 0.f) { int s = atomicAdd(&sm.cnt, 1); if (s < CAP) nbr[row * CAP + s] = j4 * 4 + 1; }
            if (v.z > 0.f) { int s = atomicAdd(&sm.cnt, 1); if (s < CAP) nbr[row * CAP + s] = j4 * 4 + 2; }
            if (v.w > 0.f) { int s = atomicAdd(&sm.cnt, 1); if (s < CAP) nbr[row * CAP + s] = j4 * 4 + 3; }
        }
        __syncthreads();
        if (tid == 0) deg[row] = sm.cnt < CAP ? sm.cnt : CAP;
        __syncthreads();
    }

    // ---- A3: pad params ----
    {
        int idx = blockIdx.x * 256 + tid;
        if (idx < 256 * NCPAD) {
            int k = idx >> 7, c = idx & 127;
            Wpad[idx] = (c < NCLASS) ? Wout[k * NCLASS + c] : 0.f;
        }
        if (blockIdx.x == 0) {
            int c = tid & 127;
            float v = 0.f;
            if (c < NCLASS) v = (tid < 128) ? aout[c] : aout[NCLASS + c];
            apad[tid] = v;
        }
    }
}

// ---------------------------------------------------------------------------
// Kernel B: layer-1 sparse softmax (4 heads packed) + aggregate + ELU.
// ONE WAVE PER NODE; per edge one 512 B fp16 row fetch serves all 4 heads.
// ---------------------------------------------------------------------------
__global__ __launch_bounds__(256) void attn_agg1(const int* __restrict__ nbr,
                                                 const int* __restrict__ deg,
                                                 const f16* __restrict__ Wh1h,
                                                 const float* __restrict__ fs1t,
                                                 const float* __restrict__ fd1t,
                                                 float* __restrict__ hcat) {
    int w = threadIdx.x >> 6, lane = threadIdx.x & 63;
    int i = blockIdx.x * 4 + w;
    __shared__ int nbrs[4][CAP];
    __shared__ float pbuf[4][CAP][4];   // per-edge per-head softmax numerators
    int dg = deg[i];
    for (int t = lane; t < dg; t += 64)
        nbrs[w][t] = nbr[i * CAP + t];
    f32x4 fsi = *(const f32x4*)(fs1t + (size_t)i * 4);
    f32x4 e[4];
    f32x4 m4 = splat4(-3.4e38f);
#pragma unroll
    for (int k = 0; k < 4; k++) {
        int t = lane + (k << 6);
        if (t < dg) {
            int j = nbrs[w][t];                         // own lane's writes
            f32x4 fdj = *(const f32x4*)(fd1t + (size_t)j * 4);
            f32x4 ev;
            ev.x = lrelu(fsi.x + fdj.x);
            ev.y = lrelu(fsi.y + fdj.y);
            ev.z = lrelu(fsi.z + fdj.z);
            ev.w = lrelu(fsi.w + fdj.w);
            e[k] = ev;
            m4.x = fmaxf(m4.x, ev.x); m4.y = fmaxf(m4.y, ev.y);
            m4.z = fmaxf(m4.z, ev.z); m4.w = fmaxf(m4.w, ev.w);
        }
    }
#pragma unroll
    for (int o = 32; o > 0; o >>= 1) {
        m4.x = fmaxf(m4.x, __shfl_xor(m4.x, o));
        m4.y = fmaxf(m4.y, __shfl_xor(m4.y, o));
        m4.z = fmaxf(m4.z, __shfl_xor(m4.z, o));
        m4.w = fmaxf(m4.w, __shfl_xor(m4.w, o));
    }
    f32x4 s4 = splat4(0.f);
#pragma unroll
    for (int k = 0; k < 4; k++) {
        int t = lane + (k << 6);
        if (t < dg) {
            f32x4 p;
            p.x = __expf(e[k].x - m4.x);
            p.y = __expf(e[k].y - m4.y);
            p.z = __expf(e[k].z - m4.z);
            p.w = __expf(e[k].w - m4.w);
            *(f32x4*)&pbuf[w][t][0] = p;
            s4 += p;
        }
    }
#pragma unroll
    for (int o = 32; o > 0; o >>= 1) {
        s4.x += __shfl_xor(s4.x, o);
        s4.y += __shfl_xor(s4.y, o);
        s4.z += __shfl_xor(s4.z, o);
        s4.w += __shfl_xor(s4.w, o);
    }
    __syncthreads();  // nbrs + pbuf cross-lane visibility
    int hl = lane >> 4;
    const f16* wrow = Wh1h + 4 * lane;
    f32x4 acc = splat4(0.f);
#pragma unroll 8
    for (int t = 0; t < dg; t++) {
        int j = nbrs[w][t];
        float p = pbuf[w][t][hl];
        f16x4 wv = *(const f16x4*)(wrow + (size_t)j * (NHEADS * NHID));
        acc += __builtin_convertvector(wv, f32x4) * splat4(p);
    }
    float sh = hl == 0 ? s4.x : hl == 1 ? s4.y : hl == 2 ? s4.z : s4.w;
    acc.x /= sh; acc.y /= sh; acc.z /= sh; acc.w /= sh;
    acc.x = acc.x > 0.f ? acc.x : expm1f(acc.x);
    acc.y = acc.y > 0.f ? acc.y : expm1f(acc.y);
    acc.z = acc.z > 0.f ? acc.z : expm1f(acc.z);
    acc.w = acc.w > 0.f ? acc.w : expm1f(acc.w);
    *(f32x4*)(hcat + (size_t)i * (NHEADS * NHID) + 4 * lane) = acc;
}

// ---------------------------------------------------------------------------
// Kernel C: gemm2 (64-row tiles) + fused coef2 epilogue. fp16 Wh2h output.
// ---------------------------------------------------------------------------
__global__ __launch_bounds__(256) void phaseC(const float* __restrict__ hcat,
                                              const float* __restrict__ Wpad,
                                              const float* __restrict__ apad,
                                              f16* __restrict__ Wh2h,
                                              float* __restrict__ fs2,
                                              float* __restrict__ fd2) {
    int r0 = blockIdx.x * 64;
    __shared__ float xs[64][260];
    for (int t = threadIdx.x; t < 64 * 64; t += 256) {
        int r = t >> 6, c4 = t & 63;
        *(float4*)&xs[r][c4 * 4] = *(const float4*)(hcat + (size_t)(r0 + r) * 256 + c4 * 4);
    }
    __syncthreads();
    int c0 = (threadIdx.x & 63) * 2;
    int rb = (threadIdx.x >> 6) * 16;
    float acc0[16] = {}, acc1[16] = {};
    for (int k4 = 0; k4 < 256; k4 += 4) {
        float2 b0 = *(const float2*)&Wpad[(k4 + 0) * NCPAD + c0];
        float2 b1 = *(const float2*)&Wpad[(k4 + 1) * NCPAD + c0];
        float2 b2 = *(const float2*)&Wpad[(k4 + 2) * NCPAD + c0];
        float2 b3 = *(const float2*)&Wpad[(k4 + 3) * NCPAD + c0];
#pragma unroll
        for (int r = 0; r < 16; r++) {
            float4 a = *(const float4*)&xs[rb + r][k4];
            acc0[r] += a.x * b0.x + a.y * b1.x + a.z * b2.x + a.w * b3.x;
            acc1[r] += a.x * b0.y + a.y * b1.y + a.z * b2.y + a.w * b3.y;
        }
    }
    float as0 = apad[c0], as1 = apad[c0 + 1];
    float ad0 = apad[128 + c0], ad1 = apad[128 + c0 + 1];
#pragma unroll
    for (int r = 0; r < 16; r++) {
        int row = r0 + rb + r;
        f16* p = &Wh2h[(size_t)row * NCPAD + c0];
        p[0] = (f16)acc0[r]; p[1] = (f16)acc1[r];
        float s = acc0[r] * as0 + acc1[r] * as1;
        float dd = acc0[r] * ad0 + acc1[r] * ad1;
#pragma unroll
        for (int o = 32; o > 0; o >>= 1) { s += __shfl_xor(s, o); dd += __shfl_xor(dd, o); }
        if ((threadIdx.x & 63) == 0) { fs2[row] = s; fd2[row] = dd; }
    }
}

// ---------------------------------------------------------------------------
// Kernel D: layer-2 sparse softmax + aggregate. ONE WAVE PER NODE; 2 edges/iter.
// ---------------------------------------------------------------------------
__global__ __launch_bounds__(256) void attn_agg2(const int* __restrict__ nbr,
                                                 const int* __restrict__ deg,
                                                 const f16* __restrict__ Wh2h,
                                                 const float* __restrict__ fs2,
                                                 const float* __restrict__ fd2,
                                                 float* __restrict__ out) {
    int w = threadIdx.x >> 6, lane = threadIdx.x & 63;
    int i = blockIdx.x * 4 + w;
    __shared__ int nbrs[4][CAP];
    __shared__ float pbuf[4][CAP];
    int dg = deg[i];
    for (int t = lane; t < dg; t += 64)
        nbrs[w][t] = nbr[i * CAP + t];
    float fsi = fs2[i];
    float e[4];
    float m = -3.4e38f;
#pragma unroll
    for (int k = 0; k < 4; k++) {
        int t = lane + (k << 6);
        if (t < dg) {
            float ev = lrelu(fsi + fd2[nbrs[w][t]]);
            e[k] = ev;
            m = fmaxf(m, ev);
        }
    }
#pragma unroll
    for (int o = 32; o > 0; o >>= 1) m = fmaxf(m, __shfl_xor(m, o));
    float s = 0.f;
#pragma unroll
    for (int k = 0; k < 4; k++) {
        int t = lane + (k << 6);
        if (t < dg) {
            float p = __expf(e[k] - m);
            pbuf[w][t] = p;
            s += p;
        }
    }
#pragma unroll
    for (int o = 32; o > 0; o >>= 1) s += __shfl_xor(s, o);
    __syncthreads();  // nbrs + pbuf cross-lane visibility
    int eg = lane >> 5, c = lane & 31;
    const f16* wrow = Wh2h + 4 * c;
    f32x4 acc = splat4(0.f);
#pragma unroll 4
    for (int tt = 0; tt < dg; tt += 2) {
        int t = tt + eg;
        int tc = t < dg ? t : 0;         // dg >= 1 (self-loop)
        float p = t < dg ? pbuf[w][tc] : 0.f;
        int j = nbrs[w][tc];
        f16x4 wv = *(const f16x4*)(wrow + (size_t)j * NCPAD);
        acc += __builtin_convertvector(wv, f32x4) * splat4(p);
    }
    acc.x += __shfl_xor(acc.x, 32);
    acc.y += __shfl_xor(acc.y, 32);
    acc.z += __shfl_xor(acc.z, 32);
    acc.w += __shfl_xor(acc.w, 32);
    if (eg == 0) {
        int c4 = c * 4;
#pragma unroll
        for (int q = 0; q < 4; q++)
            if (c4 + q < NCLASS) out[(size_t)i * NCLASS + c4 + q] = acc[q] / s;
    }
}

// ---------------------------------------------------------------------------

extern "C" void kernel_launch(void* const* d_in, const int* in_sizes, int n_in,
                              void* d_out, int out_size, void* d_ws, size_t ws_size,
                              hipStream_t stream) {
    const float* x       = (const float*)d_in[0];  // [8192,256]
    const float* adj     = (const float*)d_in[1];  // [8192,8192]
    const float* Ws      = (const float*)d_in[2];  // [4,256,64]
    const float* a_heads = (const float*)d_in[3];  // [4,128]
    const float* Wout    = (const float*)d_in[4];  // [256,121]
    const float* aout    = (const float*)d_in[5];  // [242]
    float* out = (float*)d_out;                    // [8192,121]

    char* ws = (char*)d_ws;
    size_t off = 0;
    auto alloc = [&](size_t bytes) { void* p = ws + off; off = (off + bytes + 255) & ~(size_t)255; return p; };
    int*   nbr  = (int*)  alloc((size_t)N_NODES * CAP * 4);            // 8 MB
    int*   deg  = (int*)  alloc((size_t)N_NODES * 4);                  // 32 KB
    f16*   Wh1h = (f16*)  alloc((size_t)N_NODES * NHEADS * NHID * 2);  // 4 MB fp16
    float* fs1t = (float*)alloc((size_t)N_NODES * 4 * 4);              // 128 KB
    float* fd1t = (float*)alloc((size_t)N_NODES * 4 * 4);              // 128 KB
    float* hcat = (float*)alloc((size_t)N_NODES * NHEADS * NHID * 4);  // 8 MB fp32
    f16*   Wh2h = (f16*)  alloc((size_t)N_NODES * NCPAD * 2);          // 2 MB fp16
    float* fs2  = (float*)alloc((size_t)N_NODES * 4);
    float* fd2  = (float*)alloc((size_t)N_NODES * 4);
    float* Wpad = (float*)alloc((size_t)256 * NCPAD * 4);
    float* apad = (float*)alloc((size_t)256 * 4);

    phaseA<<<1024, 256, 0, stream>>>(x, adj, Ws, a_heads, Wout, aout,
                                     nbr, deg, Wh1h, fs1t, fd1t, Wpad, apad);
    attn_agg1<<<N_NODES / 4, 256, 0, stream>>>(nbr, deg, Wh1h, fs1t, fd1t, hcat);
    phaseC<<<N_NODES / 64, 256, 0, stream>>>(hcat, Wpad, apad, Wh2h, fs2, fd2);
    attn_agg2<<<N_NODES / 4, 256, 0, stream>>>(nbr, deg, Wh2h, fs2, fd2, out);
}

// Round 9
// 500.075 us; speedup vs baseline: 1.1206x; 1.1206x over previous
//
#include <hip/hip_runtime.h>
#include <math.h>

#define N_NODES 8192
#define NFEAT 256
#define NHID 64
#define NHEADS 4
#define NCLASS 121
#define NCPAD 128
#define CAP 256
#define LRALPHA 0.2f

typedef float f32x4 __attribute__((ext_vector_type(4)));

__device__ __forceinline__ float lrelu(float x) { return x > 0.f ? x : LRALPHA * x; }
__device__ __forceinline__ f32x4 splat4(float v) { f32x4 r = {v, v, v, v}; return r; }

// ---------------------------------------------------------------------------
// K1: build per-row neighbor lists from dense adjacency (one block per row,
// 8192 blocks, 4 B LDS -> full occupancy streaming).
// ---------------------------------------------------------------------------
__global__ __launch_bounds__(256) void build_csr(const float* __restrict__ adj,
                                                 int* __restrict__ nbr,
                                                 int* __restrict__ deg) {
    int row = blockIdx.x;
    __shared__ int cnt;
    if (threadIdx.x == 0) cnt = 0;
    __syncthreads();
    const f32x4* arow = (const f32x4*)(adj + (size_t)row * N_NODES);
    for (int j4 = threadIdx.x; j4 < N_NODES / 4; j4 += 256) {
        f32x4 v = __builtin_nontemporal_load(&arow[j4]);
        if (v.x > 0.f) { int s = atomicAdd(&cnt, 1); if (s < CAP) nbr[row * CAP + s] = j4 * 4 + 0; }
        if (v.y > 0.f) { int s = atomicAdd(&cnt, 1); if (s < CAP) nbr[row * CAP + s] = j4 * 4 + 1; }
        if (v.z > 0.f) { int s = atomicAdd(&cnt, 1); if (s < CAP) nbr[row * CAP + s] = j4 * 4 + 2; }
        if (v.w > 0.f) { int s = atomicAdd(&cnt, 1); if (s < CAP) nbr[row * CAP + s] = j4 * 4 + 3; }
    }
    __syncthreads();
    if (threadIdx.x == 0) deg[row] = cnt < CAP ? cnt : CAP;
}

// ---------------------------------------------------------------------------
// K2: pad W_out [256,121] -> [256,128] (zeros) and a_out [242] -> [256].
// ---------------------------------------------------------------------------
__global__ __launch_bounds__(256) void pad_params(const float* __restrict__ Wout,
                                                  const float* __restrict__ aout,
                                                  float* __restrict__ Wpad,
                                                  float* __restrict__ apad) {
    int idx = blockIdx.x * 256 + threadIdx.x;
    if (idx < 256 * NCPAD) {
        int k = idx >> 7, c = idx & 127;
        Wpad[idx] = (c < NCLASS) ? Wout[k * NCLASS + c] : 0.f;
    }
    if (idx < 256) {
        int c = idx & 127;
        float v = 0.f;
        if (c < NCLASS) v = (idx < 128) ? aout[c] : aout[NCLASS + c];
        apad[idx] = v;
    }
}

// ---------------------------------------------------------------------------
// K3: layer-1 GEMM + fused coef1 epilogue. Output INTERLEAVED Wh1[i][h*64+d]
// (1 KB rows), PLAIN stores (NT regressed, r4). fs1t/fd1t node-major float4.
// ---------------------------------------------------------------------------
__global__ __launch_bounds__(256) void gemm1(const float* __restrict__ x,
                                             const float* __restrict__ Ws,
                                             const float* __restrict__ a_heads,
                                             float* __restrict__ Wh1,
                                             float* __restrict__ fs1t,
                                             float* __restrict__ fd1t) {
    int h = blockIdx.y;
    int r0 = blockIdx.x * 64;
    __shared__ float xs[64][260];
    for (int t = threadIdx.x; t < 64 * 64; t += 256) {
        int r = t >> 6, c4 = t & 63;
        *(float4*)&xs[r][c4 * 4] = *(const float4*)(x + (size_t)(r0 + r) * NFEAT + c4 * 4);
    }
    __syncthreads();
    int d = threadIdx.x & 63;
    int rb = (threadIdx.x >> 6) * 16;
    const float* W = Ws + (size_t)h * NFEAT * NHID + d;  // W[k][d]
    float acc[16] = {};
    for (int k4 = 0; k4 < NFEAT; k4 += 4) {
        float b0 = W[(k4 + 0) * NHID];
        float b1 = W[(k4 + 1) * NHID];
        float b2 = W[(k4 + 2) * NHID];
        float b3 = W[(k4 + 3) * NHID];
#pragma unroll
        for (int r = 0; r < 16; r++) {
            float4 a = *(const float4*)&xs[rb + r][k4];
            acc[r] += a.x * b0 + a.y * b1 + a.z * b2 + a.w * b3;
        }
    }
    float ah_s = a_heads[h * 2 * NHID + d];
    float ah_d = a_heads[h * 2 * NHID + NHID + d];
#pragma unroll
    for (int r = 0; r < 16; r++) {
        int row = r0 + rb + r;
        Wh1[(size_t)row * (NHEADS * NHID) + h * NHID + d] = acc[r];
        float s = acc[r] * ah_s;
        float dd = acc[r] * ah_d;
#pragma unroll
        for (int o = 32; o > 0; o >>= 1) { s += __shfl_xor(s, o); dd += __shfl_xor(dd, o); }
        if (d == 0) { fs1t[(size_t)row * 4 + h] = s; fd1t[(size_t)row * 4 + h] = dd; }
    }
}

// ---------------------------------------------------------------------------
// K4: layer-1 sparse softmax (4 heads packed) + aggregate + ELU.
// ONE WAVE PER NODE; per edge one global_load_dwordx4 fetches the 1 KB row
// Wh1[j][0:256] (lane l -> head l>>4, dims 4l..4l+3). Unroll 16 for MLP.
// ---------------------------------------------------------------------------
__global__ __launch_bounds__(256) void attn_agg1(const int* __restrict__ nbr,
                                                 const int* __restrict__ deg,
                                                 const float* __restrict__ Wh1,
                                                 const float* __restrict__ fs1t,
                                                 const float* __restrict__ fd1t,
                                                 float* __restrict__ hcat) {
    int w = threadIdx.x >> 6, lane = threadIdx.x & 63;
    int i = blockIdx.x * 4 + w;
    __shared__ int nbrs[4][CAP];
    __shared__ float pbuf[4][CAP][4];   // per-edge per-head softmax numerators
    int dg = deg[i];
    for (int t = lane; t < dg; t += 64)
        nbrs[w][t] = nbr[i * CAP + t];
    f32x4 fsi = *(const f32x4*)(fs1t + (size_t)i * 4);
    f32x4 e[4];
    f32x4 m4 = splat4(-3.4e38f);
#pragma unroll
    for (int k = 0; k < 4; k++) {
        int t = lane + (k << 6);
        if (t < dg) {
            int j = nbrs[w][t];                         // own lane's writes
            f32x4 fdj = *(const f32x4*)(fd1t + (size_t)j * 4);
            f32x4 ev;
            ev.x = lrelu(fsi.x + fdj.x);
            ev.y = lrelu(fsi.y + fdj.y);
            ev.z = lrelu(fsi.z + fdj.z);
            ev.w = lrelu(fsi.w + fdj.w);
            e[k] = ev;
            m4.x = fmaxf(m4.x, ev.x); m4.y = fmaxf(m4.y, ev.y);
            m4.z = fmaxf(m4.z, ev.z); m4.w = fmaxf(m4.w, ev.w);
        }
    }
#pragma unroll
    for (int o = 32; o > 0; o >>= 1) {
        m4.x = fmaxf(m4.x, __shfl_xor(m4.x, o));
        m4.y = fmaxf(m4.y, __shfl_xor(m4.y, o));
        m4.z = fmaxf(m4.z, __shfl_xor(m4.z, o));
        m4.w = fmaxf(m4.w, __shfl_xor(m4.w, o));
    }
    f32x4 s4 = splat4(0.f);
#pragma unroll
    for (int k = 0; k < 4; k++) {
        int t = lane + (k << 6);
        if (t < dg) {
            f32x4 p;
            p.x = __expf(e[k].x - m4.x);
            p.y = __expf(e[k].y - m4.y);
            p.z = __expf(e[k].z - m4.z);
            p.w = __expf(e[k].w - m4.w);
            *(f32x4*)&pbuf[w][t][0] = p;
            s4 += p;
        }
    }
#pragma unroll
    for (int o = 32; o > 0; o >>= 1) {
        s4.x += __shfl_xor(s4.x, o);
        s4.y += __shfl_xor(s4.y, o);
        s4.z += __shfl_xor(s4.z, o);
        s4.w += __shfl_xor(s4.w, o);
    }
    __syncthreads();  // nbrs + pbuf cross-lane visibility
    int hl = lane >> 4;
    const float* wrow = Wh1 + 4 * lane;
    f32x4 acc = splat4(0.f);
#pragma unroll 16
    for (int t = 0; t < dg; t++) {
        int j = nbrs[w][t];
        float p = pbuf[w][t][hl];
        f32x4 wv = *(const f32x4*)(wrow + (size_t)j * (NHEADS * NHID));
        acc += wv * splat4(p);
    }
    float sh = hl == 0 ? s4.x : hl == 1 ? s4.y : hl == 2 ? s4.z : s4.w;
    acc.x /= sh; acc.y /= sh; acc.z /= sh; acc.w /= sh;
    acc.x = acc.x > 0.f ? acc.x : expm1f(acc.x);
    acc.y = acc.y > 0.f ? acc.y : expm1f(acc.y);
    acc.z = acc.z > 0.f ? acc.z : expm1f(acc.z);
    acc.w = acc.w > 0.f ? acc.w : expm1f(acc.w);
    *(f32x4*)(hcat + (size_t)i * (NHEADS * NHID) + 4 * lane) = acc;
}

// ---------------------------------------------------------------------------
// K5: layer-2 GEMM + fused coef2 epilogue. Row-major fp32 Wh2[i][128].
// ---------------------------------------------------------------------------
__global__ __launch_bounds__(256) void gemm2(const float* __restrict__ hcat,
                                             const float* __restrict__ Wpad,
                                             const float* __restrict__ apad,
                                             float* __restrict__ Wh2,
                                             float* __restrict__ fs2,
                                             float* __restrict__ fd2) {
    int r0 = blockIdx.x * 64;
    __shared__ float xs[64][260];
    for (int t = threadIdx.x; t < 64 * 64; t += 256) {
        int r = t >> 6, c4 = t & 63;
        *(float4*)&xs[r][c4 * 4] = *(const float4*)(hcat + (size_t)(r0 + r) * 256 + c4 * 4);
    }
    __syncthreads();
    int c0 = (threadIdx.x & 63) * 2;
    int rb = (threadIdx.x >> 6) * 16;
    float acc0[16] = {}, acc1[16] = {};
    for (int k4 = 0; k4 < 256; k4 += 4) {
        float2 b0 = *(const float2*)&Wpad[(k4 + 0) * NCPAD + c0];
        float2 b1 = *(const float2*)&Wpad[(k4 + 1) * NCPAD + c0];
        float2 b2 = *(const float2*)&Wpad[(k4 + 2) * NCPAD + c0];
        float2 b3 = *(const float2*)&Wpad[(k4 + 3) * NCPAD + c0];
#pragma unroll
        for (int r = 0; r < 16; r++) {
            float4 a = *(const float4*)&xs[rb + r][k4];
            acc0[r] += a.x * b0.x + a.y * b1.x + a.z * b2.x + a.w * b3.x;
            acc1[r] += a.x * b0.y + a.y * b1.y + a.z * b2.y + a.w * b3.y;
        }
    }
    float as0 = apad[c0], as1 = apad[c0 + 1];
    float ad0 = apad[128 + c0], ad1 = apad[128 + c0 + 1];
#pragma unroll
    for (int r = 0; r < 16; r++) {
        int row = r0 + rb + r;
        float2 v = make_float2(acc0[r], acc1[r]);
        *(float2*)&Wh2[(size_t)row * NCPAD + c0] = v;
        float s = acc0[r] * as0 + acc1[r] * as1;
        float dd = acc0[r] * ad0 + acc1[r] * ad1;
#pragma unroll
        for (int o = 32; o > 0; o >>= 1) { s += __shfl_xor(s, o); dd += __shfl_xor(dd, o); }
        if ((threadIdx.x & 63) == 0) { fs2[row] = s; fd2[row] = dd; }
    }
}

// ---------------------------------------------------------------------------
// K6: layer-2 sparse softmax + aggregate. ONE WAVE PER NODE; 2 edges/iter
// (lane half eg takes edge t+eg, float4 over 128 cols), halves combined by
// shfl_xor(32). Unroll 8.
// ---------------------------------------------------------------------------
__global__ __launch_bounds__(256) void attn_agg2(const int* __restrict__ nbr,
                                                 const int* __restrict__ deg,
                                                 const float* __restrict__ Wh2,
                                                 const float* __restrict__ fs2,
                                                 const float* __restrict__ fd2,
                                                 float* __restrict__ out) {
    int w = threadIdx.x >> 6, lane = threadIdx.x & 63;
    int i = blockIdx.x * 4 + w;
    __shared__ int nbrs[4][CAP];
    __shared__ float pbuf[4][CAP];
    int dg = deg[i];
    for (int t = lane; t < dg; t += 64)
        nbrs[w][t] = nbr[i * CAP + t];
    float fsi = fs2[i];
    float e[4];
    float m = -3.4e38f;
#pragma unroll
    for (int k = 0; k < 4; k++) {
        int t = lane + (k << 6);
        if (t < dg) {
            float ev = lrelu(fsi + fd2[nbrs[w][t]]);
            e[k] = ev;
            m = fmaxf(m, ev);
        }
    }
#pragma unroll
    for (int o = 32; o > 0; o >>= 1) m = fmaxf(m, __shfl_xor(m, o));
    float s = 0.f;
#pragma unroll
    for (int k = 0; k < 4; k++) {
        int t = lane + (k << 6);
        if (t < dg) {
            float p = __expf(e[k] - m);
            pbuf[w][t] = p;
            s += p;
        }
    }
#pragma unroll
    for (int o = 32; o > 0; o >>= 1) s += __shfl_xor(s, o);
    __syncthreads();  // nbrs + pbuf cross-lane visibility
    int eg = lane >> 5, c = lane & 31;
    const float* wrow = Wh2 + 4 * c;
    f32x4 acc = splat4(0.f);
#pragma unroll 8
    for (int tt = 0; tt < dg; tt += 2) {
        int t = tt + eg;
        int tc = t < dg ? t : 0;         // dg >= 1 (self-loop)
        float p = t < dg ? pbuf[w][tc] : 0.f;
        int j = nbrs[w][tc];
        f32x4 wv = *(const f32x4*)(wrow + (size_t)j * NCPAD);
        acc += wv * splat4(p);
    }
    acc.x += __shfl_xor(acc.x, 32);
    acc.y += __shfl_xor(acc.y, 32);
    acc.z += __shfl_xor(acc.z, 32);
    acc.w += __shfl_xor(acc.w, 32);
    if (eg == 0) {
        int c4 = c * 4;
#pragma unroll
        for (int q = 0; q < 4; q++)
            if (c4 + q < NCLASS) out[(size_t)i * NCLASS + c4 + q] = acc[q] / s;
    }
}

// ---------------------------------------------------------------------------

extern "C" void kernel_launch(void* const* d_in, const int* in_sizes, int n_in,
                              void* d_out, int out_size, void* d_ws, size_t ws_size,
                              hipStream_t stream) {
    const float* x       = (const float*)d_in[0];  // [8192,256]
    const float* adj     = (const float*)d_in[1];  // [8192,8192]
    const float* Ws      = (const float*)d_in[2];  // [4,256,64]
    const float* a_heads = (const float*)d_in[3];  // [4,128]
    const float* Wout    = (const float*)d_in[4];  // [256,121]
    const float* aout    = (const float*)d_in[5];  // [242]
    float* out = (float*)d_out;                    // [8192,121]

    char* ws = (char*)d_ws;
    size_t off = 0;
    auto alloc = [&](size_t bytes) { void* p = ws + off; off = (off + bytes + 255) & ~(size_t)255; return p; };
    int*   nbr  = (int*)  alloc((size_t)N_NODES * CAP * 4);            // 8 MB
    int*   deg  = (int*)  alloc((size_t)N_NODES * 4);                  // 32 KB
    float* Wh1  = (float*)alloc((size_t)N_NODES * NHEADS * NHID * 4);  // 8 MB, interleaved rows
    float* fs1t = (float*)alloc((size_t)N_NODES * 4 * 4);              // 128 KB, node-major float4
    float* fd1t = (float*)alloc((size_t)N_NODES * 4 * 4);              // 128 KB
    float* hcat = (float*)alloc((size_t)N_NODES * NHEADS * NHID * 4);  // 8 MB
    float* Wh2  = (float*)alloc((size_t)N_NODES * NCPAD * 4);          // 4 MB
    float* fs2  = (float*)alloc((size_t)N_NODES * 4);
    float* fd2  = (float*)alloc((size_t)N_NODES * 4);
    float* Wpad = (float*)alloc((size_t)256 * NCPAD * 4);
    float* apad = (float*)alloc((size_t)256 * 4);

    build_csr<<<N_NODES, 256, 0, stream>>>(adj, nbr, deg);
    pad_params<<<128, 256, 0, stream>>>(Wout, aout, Wpad, apad);
    gemm1<<<dim3(N_NODES / 64, NHEADS), 256, 0, stream>>>(x, Ws, a_heads, Wh1, fs1t, fd1t);
    attn_agg1<<<N_NODES / 4, 256, 0, stream>>>(nbr, deg, Wh1, fs1t, fd1t, hcat);
    gemm2<<<N_NODES / 64, 256, 0, stream>>>(hcat, Wpad, apad, Wh2, fs2, fd2);
    attn_agg2<<<N_NODES / 4, 256, 0, stream>>>(nbr, deg, Wh2, fs2, fd2, out);
}